// Round 1
// baseline (1583.916 us; speedup 1.0000x reference)
//
#include <hip/hip_runtime.h>

// Problem constants (from reference)
#define NUM_F   26
#define DIM     128
#define NROWS   100000
#define BATCH   4096
#define TLEN    81920   // B * L indices per feature

// One 64-lane wave per (feature, bag). Lane i accumulates columns 2i, 2i+1.
// 256-thread block = 4 waves = 4 bags.
__global__ __launch_bounds__(256) void ebag_kernel(
    const float* __restrict__ tables,   // [F, N, D] fp32
    const int*   __restrict__ values,   // [F, T] int32
    const int*   __restrict__ offsets,  // [F, B+1] int32
    float*       __restrict__ out)      // [B, F, D] fp32
{
    const int wid  = blockIdx.x * 4 + (threadIdx.x >> 6);   // global wave id
    const int lane = threadIdx.x & 63;
    if (wid >= NUM_F * BATCH) return;

    const int f = wid >> 12;            // wid / BATCH  (feature-major for L3 locality)
    const int b = wid & (BATCH - 1);    // wid % BATCH

    const int off_base = f * (BATCH + 1) + b;
    const int start = offsets[off_base];
    const int end   = offsets[off_base + 1];

    const float* __restrict__ tab  = tables + (size_t)f * NROWS * DIM;
    const int*   __restrict__ vals = values + (size_t)f * TLEN;

    float ax = 0.0f, ay = 0.0f;

    // Process the bag in chunks of <=64 indices: lanes cooperatively load
    // indices, then broadcast each via readlane (SGPR) so the row loads are
    // scalar-based, coalesced, and independent across the inner loop.
    for (int i0 = start; i0 < end; i0 += 64) {
        const int cnt = min(64, end - i0);
        int myidx = 0;
        if (i0 + lane < end) myidx = vals[i0 + lane];

        int j = 0;
        // Unrolled by 4 for memory-level parallelism
        for (; j + 4 <= cnt; j += 4) {
            const int idx0 = __builtin_amdgcn_readlane(myidx, j + 0);
            const int idx1 = __builtin_amdgcn_readlane(myidx, j + 1);
            const int idx2 = __builtin_amdgcn_readlane(myidx, j + 2);
            const int idx3 = __builtin_amdgcn_readlane(myidx, j + 3);
            const float2 v0 = ((const float2*)(tab + (size_t)idx0 * DIM))[lane];
            const float2 v1 = ((const float2*)(tab + (size_t)idx1 * DIM))[lane];
            const float2 v2 = ((const float2*)(tab + (size_t)idx2 * DIM))[lane];
            const float2 v3 = ((const float2*)(tab + (size_t)idx3 * DIM))[lane];
            ax += v0.x + v1.x + v2.x + v3.x;
            ay += v0.y + v1.y + v2.y + v3.y;
        }
        for (; j < cnt; ++j) {
            const int idx = __builtin_amdgcn_readlane(myidx, j);
            const float2 v = ((const float2*)(tab + (size_t)idx * DIM))[lane];
            ax += v.x;
            ay += v.y;
        }
    }

    // out[b, f, :] — lane i writes columns 2i, 2i+1 (empty bags write zeros;
    // harness poisons d_out, so every element must be written).
    float2* o = (float2*)(out + ((size_t)b * NUM_F + f) * DIM);
    float2 r; r.x = ax; r.y = ay;
    o[lane] = r;
}

extern "C" void kernel_launch(void* const* d_in, const int* in_sizes, int n_in,
                              void* d_out, int out_size, void* d_ws, size_t ws_size,
                              hipStream_t stream) {
    const float* tables  = (const float*)d_in[0];
    const int*   values  = (const int*)d_in[1];
    const int*   offsets = (const int*)d_in[2];
    float*       out     = (float*)d_out;

    const int total_waves = NUM_F * BATCH;          // 106,496 bags
    const int blocks = total_waves / 4;             // 4 waves per 256-thr block
    ebag_kernel<<<dim3(blocks), dim3(256), 0, stream>>>(tables, values, offsets, out);
}